// Round 1
// baseline (2648.205 us; speedup 1.0000x reference)
//
#include <hip/hip_runtime.h>
#include <hip/hip_bf16.h>

#define H 1024
#define G4 4096
#define EDIM 256
#define BATCH 64
#define VOUT 32000

typedef __attribute__((ext_vector_type(8))) short bh8;
typedef __attribute__((ext_vector_type(4))) float f4;

__device__ __forceinline__ unsigned short f2bf(float f) {
  unsigned u = __float_as_uint(f);
  unsigned r = (u + 0x7fffu + ((u >> 16) & 1u)) >> 16;
  return (unsigned short)r;
}

// ---------------- elementwise helpers ----------------
__global__ void k_cvt(const float* __restrict__ s, unsigned short* __restrict__ d, int n8) {
  int i = blockIdx.x * 256 + threadIdx.x;
  if (i >= n8) return;
  const float4* sp = (const float4*)s;
  float4 a = sp[2 * (size_t)i];
  float4 b = sp[2 * (size_t)i + 1];
  bh8 o;
  o[0] = (short)f2bf(a.x); o[1] = (short)f2bf(a.y);
  o[2] = (short)f2bf(a.z); o[3] = (short)f2bf(a.w);
  o[4] = (short)f2bf(b.x); o[5] = (short)f2bf(b.y);
  o[6] = (short)f2bf(b.z); o[7] = (short)f2bf(b.w);
  *(bh8*)(d + 8 * (size_t)i) = o;
}

__global__ void k_bias(const float* __restrict__ bi, const float* __restrict__ bh,
                       float* __restrict__ out) {
  int i = blockIdx.x * 256 + threadIdx.x;
  out[i] = bi[i] + bh[i];
}

__global__ void k_zero(float4* __restrict__ p, int n4) {
  int i = blockIdx.x * 256 + threadIdx.x;
  if (i < n4) p[i] = make_float4(0.f, 0.f, 0.f, 0.f);
}

// gather embedding rows -> bf16 [rows][256]
__global__ void k_gather(const int* __restrict__ idx, const float* __restrict__ emb,
                         unsigned short* __restrict__ out, int rows) {
  int t = blockIdx.x * 256 + threadIdx.x;
  int r = t >> 5, c8 = (t & 31) * 8;
  if (r >= rows) return;
  const float* e = emb + (size_t)idx[r] * EDIM + c8;
  bh8 o;
#pragma unroll
  for (int j = 0; j < 8; j++) o[j] = (short)f2bf(e[j]);
  *(bh8*)(out + (size_t)r * EDIM + c8) = o;
}

// ---------------- bf16 NT GEMM: C[m,n] = sum_k A[m,k]*B[n,k] + bias[n] ----------------
#define BM 128
#define BN 128
#define BKK 64
#define LDT 72  // padded LDS stride (elems), 144 B = 16B-aligned rows, bank-spread

__launch_bounds__(256)
__global__ void k_gemm(const unsigned short* __restrict__ A, const unsigned short* __restrict__ B,
                       float* __restrict__ C, const float* __restrict__ bias,
                       int K, int ldc, int row_off, int m_valid) {
  __shared__ __align__(16) unsigned short As[BM * LDT];
  __shared__ __align__(16) unsigned short Bs[BM * LDT];
  int tm = blockIdx.y, tn = blockIdx.x;
  int tid = threadIdx.x;
  int lane = tid & 63, wv = tid >> 6;
  int wm = (wv >> 1) * 64, wn = (wv & 1) * 64;
  f4 acc[4][4] = {};
  const size_t a_base = (size_t)tm * BM * K;
  const size_t b_base = (size_t)tn * BN * K;
  for (int k0 = 0; k0 < K; k0 += BKK) {
#pragma unroll
    for (int i = 0; i < 4; i++) {
      int u = i * 256 + tid;        // 0..1023
      int row = u >> 3;             // 0..127
      int ch = (u & 7) * 8;         // elem offset within 64-wide k tile
      bh8 va = *(const bh8*)(A + a_base + (size_t)row * K + k0 + ch);
      bh8 vb = *(const bh8*)(B + b_base + (size_t)row * K + k0 + ch);
      *(bh8*)(As + row * LDT + ch) = va;
      *(bh8*)(Bs + row * LDT + ch) = vb;
    }
    __syncthreads();
#pragma unroll
    for (int kk = 0; kk < 2; kk++) {
      int ko = kk * 32 + (lane >> 4) * 8;
      bh8 af[4], bfr[4];
#pragma unroll
      for (int x = 0; x < 4; x++) {
        af[x]  = *(const bh8*)(As + (wm + x * 16 + (lane & 15)) * LDT + ko);
        bfr[x] = *(const bh8*)(Bs + (wn + x * 16 + (lane & 15)) * LDT + ko);
      }
#pragma unroll
      for (int mi = 0; mi < 4; mi++)
#pragma unroll
        for (int ni = 0; ni < 4; ni++)
          acc[mi][ni] = __builtin_amdgcn_mfma_f32_16x16x32_bf16(af[mi], bfr[ni], acc[mi][ni], 0, 0, 0);
    }
    __syncthreads();
  }
  int r0 = tm * BM + wm + (lane >> 4) * 4;
  int c0 = tn * BN + wn + (lane & 15);
#pragma unroll
  for (int mi = 0; mi < 4; mi++) {
#pragma unroll
    for (int ni = 0; ni < 4; ni++) {
      int col = c0 + ni * 16;
      float bv = bias ? bias[col] : 0.f;
#pragma unroll
      for (int j = 0; j < 4; j++) {
        int row = r0 + mi * 16 + j;
        if (row < m_valid)
          C[(size_t)(row_off + row) * ldc + col] = acc[mi][ni][j] + bv;
      }
    }
  }
}

// ---------------- LSTM step: gates = xg[t] + h_prev @ Whh^T ; pointwise ----------------
struct Job {
  const float* xg;             // [64][4096] slice for this t
  const unsigned short* hprev; // [64][1024] bf16
  unsigned short* hnext;       // [64][1024] bf16
  float* c;                    // [64][1024] fp32 state (in/out)
  const unsigned short* Whh;   // [4096][1024] bf16
  unsigned short* yout;        // [64][1024] bf16 or nullptr
};
struct Job2 { Job j[2]; };

#define LDW 1032  // 1024+8 elems, 2064 B rows (16B aligned, bank-spread)

__launch_bounds__(256)
__global__ void k_step(Job2 jobs) {
  __shared__ __align__(16) unsigned short Ws[32 * LDW];  // 66 KB
  __shared__ float Gs[64 * 33];                           // 8.4 KB
  const Job& jb = jobs.j[blockIdx.x >> 7];
  int wg = blockIdx.x & 127;   // owns h cols [wg*8, wg*8+8)
  int tid = threadIdx.x, lane = tid & 63, wv = tid >> 6;

  // stage Whh slice: local row c in [0,32): global row = (c>>3)*1024 + wg*8 + (c&7)
#pragma unroll
  for (int i = 0; i < 16; i++) {
    int u = i * 256 + tid;       // 0..4095
    int row = u >> 7;            // 0..31
    int ch = (u & 127) * 8;      // elem offset in 1024-wide row
    int grow = ((row >> 3) << 10) + wg * 8 + (row & 7);
    bh8 v = *(const bh8*)(jb.Whh + (size_t)grow * H + ch);
    *(bh8*)(Ws + row * LDW + ch) = v;
  }
  __syncthreads();

  // GEMM: out 64x32; wave wv -> rows [wv*16, wv*16+16), N-frags 0,1
  f4 acc0 = {}, acc1 = {};
  const unsigned short* hp = jb.hprev + (size_t)(wv * 16 + (lane & 15)) * H + (lane >> 4) * 8;
  const unsigned short* wp0 = Ws + (lane & 15) * LDW + (lane >> 4) * 8;
  const unsigned short* wp1 = Ws + (16 + (lane & 15)) * LDW + (lane >> 4) * 8;
#pragma unroll 8
  for (int kk = 0; kk < 32; kk++) {
    bh8 a  = *(const bh8*)(hp + kk * 32);
    bh8 b0 = *(const bh8*)(wp0 + kk * 32);
    bh8 b1 = *(const bh8*)(wp1 + kk * 32);
    acc0 = __builtin_amdgcn_mfma_f32_16x16x32_bf16(a, b0, acc0, 0, 0, 0);
    acc1 = __builtin_amdgcn_mfma_f32_16x16x32_bf16(a, b1, acc1, 0, 0, 0);
  }
#pragma unroll
  for (int j = 0; j < 4; j++) {
    int r = wv * 16 + (lane >> 4) * 4 + j;
    Gs[r * 33 + (lane & 15)]      = acc0[j];
    Gs[r * 33 + 16 + (lane & 15)] = acc1[j];
  }
  __syncthreads();

  // pointwise: 64 rows x 8 h-cols = 512 outputs, 2 per thread
#pragma unroll
  for (int q = 0; q < 2; q++) {
    int idx = q * 256 + tid;
    int r = idx >> 3, hc = idx & 7;
    int gcb = wg * 8 + hc;
    float gi = Gs[r * 33 + hc]      + jb.xg[(size_t)r * G4 + gcb];
    float gf = Gs[r * 33 + 8 + hc]  + jb.xg[(size_t)r * G4 + 1024 + gcb];
    float gg = Gs[r * 33 + 16 + hc] + jb.xg[(size_t)r * G4 + 2048 + gcb];
    float go = Gs[r * 33 + 24 + hc] + jb.xg[(size_t)r * G4 + 3072 + gcb];
    float si = 1.f / (1.f + __expf(-gi));
    float sf = 1.f / (1.f + __expf(-gf));
    float so = 1.f / (1.f + __expf(-go));
    float tg = tanhf(gg);
    int ci = r * H + gcb;
    float cv = sf * jb.c[ci] + si * tg;
    float hv = so * tanhf(cv);
    jb.c[ci] = cv;
    unsigned short hb = f2bf(hv);
    jb.hnext[ci] = hb;
    if (jb.yout) jb.yout[ci] = hb;
  }
}

// ---------------- host ----------------
extern "C" void kernel_launch(void* const* d_in, const int* in_sizes, int n_in,
                              void* d_out, int out_size, void* d_ws, size_t ws_size,
                              hipStream_t stream) {
  const int*   src     = (const int*)d_in[0];
  const int*   tgt     = (const int*)d_in[1];
  const float* enc_emb = (const float*)d_in[2];
  const float* dec_emb = (const float*)d_in[3];
  const float* fc_W    = (const float*)d_in[4];
  const float* fc_b    = (const float*)d_in[5];
  const float* eW_ih0  = (const float*)d_in[6];
  const float* eW_hh0  = (const float*)d_in[7];
  const float* eb_ih0  = (const float*)d_in[8];
  const float* eb_hh0  = (const float*)d_in[9];
  const float* eW_ih1  = (const float*)d_in[10];
  const float* eW_hh1  = (const float*)d_in[11];
  const float* eb_ih1  = (const float*)d_in[12];
  const float* eb_hh1  = (const float*)d_in[13];
  const float* dW_ih0  = (const float*)d_in[14];
  const float* dW_hh0  = (const float*)d_in[15];
  const float* db_ih0  = (const float*)d_in[16];
  const float* db_hh0  = (const float*)d_in[17];
  const float* dW_ih1  = (const float*)d_in[18];
  const float* dW_hh1  = (const float*)d_in[19];
  const float* db_ih1  = (const float*)d_in[20];
  const float* db_hh1  = (const float*)d_in[21];

  char* p = (char*)d_ws;
  auto alloc = [&](size_t b) { char* r = p; p += (b + 255) & ~(size_t)255; return r; };

  // zero-arena: [hbf_e0_0 | hbf_e1_0 | c_e0 | c_e1] contiguous = 768 KB
  char* zar = alloc(131072 * 2 + 262144 * 2);
  unsigned short* hbf_e0_0 = (unsigned short*)zar;
  unsigned short* hbf_e1_0 = (unsigned short*)(zar + 131072);
  float* c_e0 = (float*)(zar + 262144);
  float* c_e1 = (float*)(zar + 524288);
  unsigned short* hbf_e0_1 = (unsigned short*)alloc(131072);
  unsigned short* hbf_e1_1 = (unsigned short*)alloc(131072);
  unsigned short* hbf_d0[2] = {(unsigned short*)alloc(131072), (unsigned short*)alloc(131072)};
  unsigned short* hbf_d1[2] = {(unsigned short*)alloc(131072), (unsigned short*)alloc(131072)};

  unsigned short* w_eih0 = (unsigned short*)alloc((size_t)G4 * EDIM * 2);
  unsigned short* w_ehh0 = (unsigned short*)alloc((size_t)G4 * H * 2);
  unsigned short* w_eih1 = (unsigned short*)alloc((size_t)G4 * H * 2);
  unsigned short* w_ehh1 = (unsigned short*)alloc((size_t)G4 * H * 2);
  unsigned short* w_dih0 = (unsigned short*)alloc((size_t)G4 * EDIM * 2);
  unsigned short* w_dhh0 = (unsigned short*)alloc((size_t)G4 * H * 2);
  unsigned short* w_dih1 = (unsigned short*)alloc((size_t)G4 * H * 2);
  unsigned short* w_dhh1 = (unsigned short*)alloc((size_t)G4 * H * 2);
  unsigned short* w_fc   = (unsigned short*)alloc((size_t)VOUT * H * 2);

  unsigned short* xe  = (unsigned short*)alloc((size_t)3072 * EDIM * 2);
  unsigned short* xd  = (unsigned short*)alloc((size_t)3072 * EDIM * 2);
  unsigned short* y0  = (unsigned short*)alloc((size_t)3072 * H * 2);
  unsigned short* d0b = (unsigned short*)alloc((size_t)3072 * H * 2);
  unsigned short* d1b = (unsigned short*)alloc((size_t)3072 * H * 2);
  float* xgA = (float*)alloc((size_t)3072 * G4 * 4);
  float* xgB = (float*)alloc((size_t)3072 * G4 * 4);
  float* bias_e0 = (float*)alloc((size_t)4 * G4 * 4);
  float* bias_e1 = bias_e0 + G4;
  float* bias_d0 = bias_e0 + 2 * G4;
  float* bias_d1 = bias_e0 + 3 * G4;

  auto cvt = [&](const float* s, unsigned short* d, size_t n) {
    int n8 = (int)(n / 8);
    k_cvt<<<dim3((n8 + 255) / 256), dim3(256), 0, stream>>>(s, d, n8);
  };
  cvt(eW_ih0, w_eih0, (size_t)G4 * EDIM);
  cvt(eW_hh0, w_ehh0, (size_t)G4 * H);
  cvt(eW_ih1, w_eih1, (size_t)G4 * H);
  cvt(eW_hh1, w_ehh1, (size_t)G4 * H);
  cvt(dW_ih0, w_dih0, (size_t)G4 * EDIM);
  cvt(dW_hh0, w_dhh0, (size_t)G4 * H);
  cvt(dW_ih1, w_dih1, (size_t)G4 * H);
  cvt(dW_hh1, w_dhh1, (size_t)G4 * H);
  cvt(fc_W,   w_fc,   (size_t)VOUT * H);

  k_bias<<<dim3(16), dim3(256), 0, stream>>>(eb_ih0, eb_hh0, bias_e0);
  k_bias<<<dim3(16), dim3(256), 0, stream>>>(eb_ih1, eb_hh1, bias_e1);
  k_bias<<<dim3(16), dim3(256), 0, stream>>>(db_ih0, db_hh0, bias_d0);
  k_bias<<<dim3(16), dim3(256), 0, stream>>>(db_ih1, db_hh1, bias_d1);

  k_zero<<<dim3(192), dim3(256), 0, stream>>>((float4*)zar, 49152);           // states
  k_zero<<<dim3(2000), dim3(256), 0, stream>>>((float4*)d_out, 512000);       // t=0 output block

  k_gather<<<dim3(384), dim3(256), 0, stream>>>(src, enc_emb, xe, 3072);
  k_gather<<<dim3(376), dim3(256), 0, stream>>>(tgt, dec_emb, xd, 3008);

  // input-transform GEMMs (xg = x @ W_ih^T + b_ih + b_hh)
  k_gemm<<<dim3(32, 24), dim3(256), 0, stream>>>(xe, w_eih0, xgA, bias_e0, EDIM, G4, 0, 3072);
  k_gemm<<<dim3(32, 24), dim3(256), 0, stream>>>(xd, w_dih0, xgB, bias_d0, EDIM, G4, 0, 3072);

  const size_t XGT = (size_t)BATCH * G4;  // per-t xg stride
  const size_t HT  = (size_t)BATCH * H;   // per-t h stride

  // encoder layer 0
  for (int t = 0; t < 48; t++) {
    Job2 jj{};
    jj.j[0].xg = xgA + (size_t)t * XGT;
    jj.j[0].hprev = (t & 1) ? hbf_e0_1 : hbf_e0_0;
    jj.j[0].hnext = (t & 1) ? hbf_e0_0 : hbf_e0_1;
    jj.j[0].c = c_e0;
    jj.j[0].Whh = w_ehh0;
    jj.j[0].yout = y0 + (size_t)t * HT;
    k_step<<<dim3(128), dim3(256), 0, stream>>>(jj);
  }
  // enc layer-1 input transform
  k_gemm<<<dim3(32, 24), dim3(256), 0, stream>>>(y0, w_eih1, xgA, bias_e1, H, G4, 0, 3072);

  // encoder layer 1 (48 steps) fused with decoder layer 0 (47 steps)
  for (int t = 0; t < 48; t++) {
    Job2 jj{};
    jj.j[0].xg = xgA + (size_t)t * XGT;
    jj.j[0].hprev = (t & 1) ? hbf_e1_1 : hbf_e1_0;
    jj.j[0].hnext = (t & 1) ? hbf_e1_0 : hbf_e1_1;
    jj.j[0].c = c_e1;
    jj.j[0].Whh = w_ehh1;
    jj.j[0].yout = nullptr;
    int nb = 128;
    if (t < 47) {
      jj.j[1].xg = xgB + (size_t)t * XGT;
      jj.j[1].hprev = (t == 0) ? hbf_e0_0 : hbf_d0[t & 1];
      jj.j[1].hnext = hbf_d0[(t + 1) & 1];
      jj.j[1].c = c_e0;             // continue encoder-0 final c state
      jj.j[1].Whh = w_dhh0;
      jj.j[1].yout = d0b + (size_t)t * HT;
      nb = 256;
    }
    k_step<<<dim3(nb), dim3(256), 0, stream>>>(jj);
  }
  // dec layer-1 input transform
  k_gemm<<<dim3(32, 24), dim3(256), 0, stream>>>(d0b, w_dih1, xgB, bias_d1, H, G4, 0, 3072);

  // decoder layer 1
  for (int t = 0; t < 47; t++) {
    Job2 jj{};
    jj.j[0].xg = xgB + (size_t)t * XGT;
    jj.j[0].hprev = (t == 0) ? hbf_e1_0 : hbf_d1[t & 1];
    jj.j[0].hnext = hbf_d1[(t + 1) & 1];
    jj.j[0].c = c_e1;               // continue encoder-1 final c state
    jj.j[0].Whh = w_dhh1;
    jj.j[0].yout = d1b + (size_t)t * HT;
    k_step<<<dim3(128), dim3(256), 0, stream>>>(jj);
  }

  // final projection into d_out rows 64..3071 (t=1..47), bias fc_b
  k_gemm<<<dim3(250, 24), dim3(256), 0, stream>>>(d1b, w_fc, (float*)d_out, fc_b, H, VOUT, 64, 3008);
}